// Round 3
// baseline (365.726 us; speedup 1.0000x reference)
//
#include <hip/hip_runtime.h>
#include <math.h>

#define DD 64
#define TK 256   // codebook tile: 256 codes x 64 dims x 4B = 64 KB LDS

typedef float f32x64 __attribute__((ext_vector_type(64)));

// ---------------- kernel 0: codebook row norms (np-bit-exact) ----------------
// numpy pairwise_sum for n=64: 8 accumulators stride-8, then pairwise combine.
__global__ __launch_bounds__(256) void cnorm_kernel(const float* __restrict__ cb,
                                                    float* __restrict__ cnorm, int K) {
    int k = blockIdx.x * 256 + threadIdx.x;
    if (k >= K) return;
    const float* row = cb + (size_t)k * DD;
    float r0 = __fmul_rn(row[0], row[0]);
    float r1 = __fmul_rn(row[1], row[1]);
    float r2 = __fmul_rn(row[2], row[2]);
    float r3 = __fmul_rn(row[3], row[3]);
    float r4 = __fmul_rn(row[4], row[4]);
    float r5 = __fmul_rn(row[5], row[5]);
    float r6 = __fmul_rn(row[6], row[6]);
    float r7 = __fmul_rn(row[7], row[7]);
#pragma unroll
    for (int i = 8; i < DD; i += 8) {
        r0 = __fadd_rn(r0, __fmul_rn(row[i + 0], row[i + 0]));
        r1 = __fadd_rn(r1, __fmul_rn(row[i + 1], row[i + 1]));
        r2 = __fadd_rn(r2, __fmul_rn(row[i + 2], row[i + 2]));
        r3 = __fadd_rn(r3, __fmul_rn(row[i + 3], row[i + 3]));
        r4 = __fadd_rn(r4, __fmul_rn(row[i + 4], row[i + 4]));
        r5 = __fadd_rn(r5, __fmul_rn(row[i + 5], row[i + 5]));
        r6 = __fadd_rn(r6, __fmul_rn(row[i + 6], row[i + 6]));
        r7 = __fadd_rn(r7, __fmul_rn(row[i + 7], row[i + 7]));
    }
    float a = __fadd_rn(r0, r1);
    float b = __fadd_rn(r2, r3);
    float c = __fadd_rn(r4, r5);
    float e = __fadd_rn(r6, r7);
    cnorm[k] = __fadd_rn(__fadd_rn(a, b), __fadd_rn(c, e));
}

// ---- np-bit-exact znorm from a register-resident point ----
__device__ __forceinline__ float znorm64(const f32x64& vz) {
    float r0 = __fmul_rn(vz[0], vz[0]);
    float r1 = __fmul_rn(vz[1], vz[1]);
    float r2 = __fmul_rn(vz[2], vz[2]);
    float r3 = __fmul_rn(vz[3], vz[3]);
    float r4 = __fmul_rn(vz[4], vz[4]);
    float r5 = __fmul_rn(vz[5], vz[5]);
    float r6 = __fmul_rn(vz[6], vz[6]);
    float r7 = __fmul_rn(vz[7], vz[7]);
#pragma unroll
    for (int i = 8; i < DD; i += 8) {
        r0 = __fadd_rn(r0, __fmul_rn(vz[i + 0], vz[i + 0]));
        r1 = __fadd_rn(r1, __fmul_rn(vz[i + 1], vz[i + 1]));
        r2 = __fadd_rn(r2, __fmul_rn(vz[i + 2], vz[i + 2]));
        r3 = __fadd_rn(r3, __fmul_rn(vz[i + 3], vz[i + 3]));
        r4 = __fadd_rn(r4, __fmul_rn(vz[i + 4], vz[i + 4]));
        r5 = __fadd_rn(r5, __fmul_rn(vz[i + 5], vz[i + 5]));
        r6 = __fadd_rn(r6, __fmul_rn(vz[i + 6], vz[i + 6]));
        r7 = __fadd_rn(r7, __fmul_rn(vz[i + 7], vz[i + 7]));
    }
    float a = __fadd_rn(r0, r1);
    float b = __fadd_rn(r2, r3);
    float c = __fadd_rn(r4, r5);
    float e = __fadd_rn(r6, r7);
    return __fadd_rn(__fadd_rn(a, b), __fadd_rn(c, e));
}

__device__ __forceinline__ void loadpt(const float* __restrict__ p, f32x64& v) {
    const float4* p4 = reinterpret_cast<const float4*>(p);
#pragma unroll
    for (int i = 0; i < DD / 4; ++i) {
        float4 t = p4[i];
        v[4 * i + 0] = t.x;
        v[4 * i + 1] = t.y;
        v[4 * i + 2] = t.z;
        v[4 * i + 3] = t.w;
    }
}

// ---------------- kernel 1: argmin over K codes, 2 points/thread -------------
// Each ds_read_b128 of a code row now feeds 8 FMAs (2 points x 4 elems),
// halving LDS-pipe demand vs round 2. Arithmetic per (point,code) is
// bit-identical to the verified rounds:
//   dot  = sequential FMA d=0..63
//   dist = fl( fma(-2,dot,znorm) + cnorm )
//   argmin: strict < in ascending k (first-min tie-break = np.argmin)
__global__ __launch_bounds__(256, 1) void argmin_kernel(const float* __restrict__ z,
                                                        const float* __restrict__ cb,
                                                        const float* __restrict__ cnorm,
                                                        float* __restrict__ outIdxF,
                                                        int N, int K) {
    __shared__ float lds_cb[TK * DD];   // 64 KB
    __shared__ float lds_cn[TK];        // 1 KB

    const int base = blockIdx.x * 512;
    const int n0 = base + threadIdx.x;
    const int n1 = base + 256 + threadIdx.x;
    const bool act0 = (n0 < N);
    const bool act1 = (n1 < N);

    f32x64 vz0, vz1;
    loadpt(z + (size_t)(act0 ? n0 : 0) * DD, vz0);
    loadpt(z + (size_t)(act1 ? n1 : 0) * DD, vz1);

    const float zn0 = znorm64(vz0);
    const float zn1 = znorm64(vz1);

    float best0 = 3.402823466e+38f, best1 = 3.402823466e+38f;
    int bidx0 = 0, bidx1 = 0;

    const int nTiles = K / TK;
    for (int t = 0; t < nTiles; ++t) {
        __syncthreads();   // previous tile fully consumed
        {   // cooperative stage: 16384 floats = 4096 float4, coalesced
            const float4* src = reinterpret_cast<const float4*>(cb + (size_t)t * TK * DD);
            float4* dst = reinterpret_cast<float4*>(lds_cb);
#pragma unroll
            for (int i = 0; i < (TK * DD / 4) / 256; ++i)
                dst[threadIdx.x + i * 256] = src[threadIdx.x + i * 256];
            if (threadIdx.x < TK)
                lds_cn[threadIdx.x] = cnorm[t * TK + threadIdx.x];
        }
        __syncthreads();

#pragma unroll 4
        for (int kk = 0; kk < TK; kk += 2) {
            const float4* cA = reinterpret_cast<const float4*>(lds_cb + kk * DD);
            const float4* cB = reinterpret_cast<const float4*>(lds_cb + (kk + 1) * DD);
            float a00 = 0.0f, a01 = 0.0f, a10 = 0.0f, a11 = 0.0f;
#pragma unroll
            for (int i = 0; i < DD / 4; ++i) {
                float4 xA = cA[i];
                float4 xB = cB[i];
                a00 = __builtin_fmaf(vz0[4 * i + 0], xA.x, a00);
                a00 = __builtin_fmaf(vz0[4 * i + 1], xA.y, a00);
                a00 = __builtin_fmaf(vz0[4 * i + 2], xA.z, a00);
                a00 = __builtin_fmaf(vz0[4 * i + 3], xA.w, a00);
                a10 = __builtin_fmaf(vz1[4 * i + 0], xA.x, a10);
                a10 = __builtin_fmaf(vz1[4 * i + 1], xA.y, a10);
                a10 = __builtin_fmaf(vz1[4 * i + 2], xA.z, a10);
                a10 = __builtin_fmaf(vz1[4 * i + 3], xA.w, a10);
                a01 = __builtin_fmaf(vz0[4 * i + 0], xB.x, a01);
                a01 = __builtin_fmaf(vz0[4 * i + 1], xB.y, a01);
                a01 = __builtin_fmaf(vz0[4 * i + 2], xB.z, a01);
                a01 = __builtin_fmaf(vz0[4 * i + 3], xB.w, a01);
                a11 = __builtin_fmaf(vz1[4 * i + 0], xB.x, a11);
                a11 = __builtin_fmaf(vz1[4 * i + 1], xB.y, a11);
                a11 = __builtin_fmaf(vz1[4 * i + 2], xB.z, a11);
                a11 = __builtin_fmaf(vz1[4 * i + 3], xB.w, a11);
            }
            float cnA = lds_cn[kk + 0];
            float cnB = lds_cn[kk + 1];
            float t00 = __fadd_rn(__builtin_fmaf(-2.0f, a00, zn0), cnA);
            float t01 = __fadd_rn(__builtin_fmaf(-2.0f, a01, zn0), cnB);
            float t10 = __fadd_rn(__builtin_fmaf(-2.0f, a10, zn1), cnA);
            float t11 = __fadd_rn(__builtin_fmaf(-2.0f, a11, zn1), cnB);
            int kb = t * TK + kk;
            if (t00 < best0) { best0 = t00; bidx0 = kb + 0; }
            if (t01 < best0) { best0 = t01; bidx0 = kb + 1; }
            if (t10 < best1) { best1 = t10; bidx1 = kb + 0; }
            if (t11 < best1) { best1 = t11; bidx1 = kb + 1; }
        }
    }
    if (act0) outIdxF[n0] = (float)bidx0;
    if (act1) outIdxF[n1] = (float)bidx1;
}

// ------------- kernel 2: gather z_q, write z_q_st, loss partials -------------
__global__ __launch_bounds__(256) void gather_kernel(const float* __restrict__ z,
                                                     const float* __restrict__ cb,
                                                     const float* __restrict__ idxF,
                                                     float* __restrict__ out0,
                                                     float* __restrict__ partials,
                                                     int N) {
    int gtid = blockIdx.x * 256 + threadIdx.x;
    int wave = gtid >> 6;
    int lane = threadIdx.x & 63;
    int nwaves = (gridDim.x * 256) >> 6;

    float acc = 0.0f;
    for (int n = wave; n < N; n += nwaves) {
        int idx = (int)idxF[n];
        float q = cb[(size_t)idx * DD + lane];
        float zv = z[(size_t)n * DD + lane];
        float t = q - zv;                       // stop_gradient(z_q - z), one round
        out0[(size_t)n * DD + lane] = zv + t;   // z + sg(z_q - z), second round
        acc += t * t;                           // loss accumulation (loose tolerance)
    }
#pragma unroll
    for (int off = 32; off; off >>= 1) acc += __shfl_xor(acc, off);

    __shared__ float ws[4];
    if (lane == 0) ws[threadIdx.x >> 6] = acc;
    __syncthreads();
    if (threadIdx.x == 0) {
        float s = (ws[0] + ws[1]) + (ws[2] + ws[3]);
        partials[blockIdx.x] = s;
    }
}

// ---------------- kernel 3: finalize loss ------------------------------------
__global__ __launch_bounds__(256) void finalize_kernel(const float* __restrict__ partials,
                                                       int nPart, float* __restrict__ lossOut,
                                                       float totalElems) {
    __shared__ float sh[256];
    float s = 0.0f;
    for (int i = threadIdx.x; i < nPart; i += 256) s += partials[i];
    sh[threadIdx.x] = s;
    __syncthreads();
    for (int stride = 128; stride; stride >>= 1) {
        if (threadIdx.x < stride) sh[threadIdx.x] += sh[threadIdx.x + stride];
        __syncthreads();
    }
    if (threadIdx.x == 0) {
        float m = sh[0] / totalElems;            // 2^23 divisor -> exact
        float p = 0.25f * m;                     // exact
        lossOut[0] = __fadd_rn(p, m);            // np op order
    }
}

extern "C" void kernel_launch(void* const* d_in, const int* in_sizes, int n_in,
                              void* d_out, int out_size, void* d_ws, size_t ws_size,
                              hipStream_t stream) {
    const float* z = (const float*)d_in[0];
    const float* cb = (const float*)d_in[1];
    const int N = in_sizes[0] / DD;   // 131072
    const int K = in_sizes[1] / DD;   // 1024

    float* out0 = (float*)d_out;                       // z_q_st: N*DD floats
    float* lossOut = out0 + (size_t)N * DD;            // 1 float
    float* outIdxF = lossOut + 1;                      // N floats (indices as f32)

    float* cnorm = (float*)d_ws;                       // K floats
    float* partials = cnorm + K;                       // 2048 floats

    cnorm_kernel<<<(K + 255) / 256, 256, 0, stream>>>(cb, cnorm, K);
    argmin_kernel<<<(N + 511) / 512, 256, 0, stream>>>(z, cb, cnorm, outIdxF, N, K);

    const int nBlocks2 = 2048;
    gather_kernel<<<nBlocks2, 256, 0, stream>>>(z, cb, outIdxF, out0, partials, N);
    finalize_kernel<<<1, 256, 0, stream>>>(partials, nBlocks2, lossOut,
                                           (float)((size_t)N * DD));
}

// Round 4
// 269.811 us; speedup vs baseline: 1.3555x; 1.3555x over previous
//
#include <hip/hip_runtime.h>
#include <math.h>

#define DD 64
#define TK 256   // codebook tile: 256 codes x 64 dims x 4B = 64 KB LDS

typedef float f32x64 __attribute__((ext_vector_type(64)));

// ---------------- kernel 0: codebook row norms (np-bit-exact) ----------------
// numpy pairwise_sum for n=64: 8 accumulators stride-8, then pairwise combine.
__global__ __launch_bounds__(256) void cnorm_kernel(const float* __restrict__ cb,
                                                    float* __restrict__ cnorm, int K) {
    int k = blockIdx.x * 256 + threadIdx.x;
    if (k >= K) return;
    const float* row = cb + (size_t)k * DD;
    float r0 = __fmul_rn(row[0], row[0]);
    float r1 = __fmul_rn(row[1], row[1]);
    float r2 = __fmul_rn(row[2], row[2]);
    float r3 = __fmul_rn(row[3], row[3]);
    float r4 = __fmul_rn(row[4], row[4]);
    float r5 = __fmul_rn(row[5], row[5]);
    float r6 = __fmul_rn(row[6], row[6]);
    float r7 = __fmul_rn(row[7], row[7]);
#pragma unroll
    for (int i = 8; i < DD; i += 8) {
        r0 = __fadd_rn(r0, __fmul_rn(row[i + 0], row[i + 0]));
        r1 = __fadd_rn(r1, __fmul_rn(row[i + 1], row[i + 1]));
        r2 = __fadd_rn(r2, __fmul_rn(row[i + 2], row[i + 2]));
        r3 = __fadd_rn(r3, __fmul_rn(row[i + 3], row[i + 3]));
        r4 = __fadd_rn(r4, __fmul_rn(row[i + 4], row[i + 4]));
        r5 = __fadd_rn(r5, __fmul_rn(row[i + 5], row[i + 5]));
        r6 = __fadd_rn(r6, __fmul_rn(row[i + 6], row[i + 6]));
        r7 = __fadd_rn(r7, __fmul_rn(row[i + 7], row[i + 7]));
    }
    float a = __fadd_rn(r0, r1);
    float b = __fadd_rn(r2, r3);
    float c = __fadd_rn(r4, r5);
    float e = __fadd_rn(r6, r7);
    cnorm[k] = __fadd_rn(__fadd_rn(a, b), __fadd_rn(c, e));
}

// ---- np-bit-exact znorm from a register-resident point ----
__device__ __forceinline__ float znorm64(const f32x64& vz) {
    float r0 = __fmul_rn(vz[0], vz[0]);
    float r1 = __fmul_rn(vz[1], vz[1]);
    float r2 = __fmul_rn(vz[2], vz[2]);
    float r3 = __fmul_rn(vz[3], vz[3]);
    float r4 = __fmul_rn(vz[4], vz[4]);
    float r5 = __fmul_rn(vz[5], vz[5]);
    float r6 = __fmul_rn(vz[6], vz[6]);
    float r7 = __fmul_rn(vz[7], vz[7]);
#pragma unroll
    for (int i = 8; i < DD; i += 8) {
        r0 = __fadd_rn(r0, __fmul_rn(vz[i + 0], vz[i + 0]));
        r1 = __fadd_rn(r1, __fmul_rn(vz[i + 1], vz[i + 1]));
        r2 = __fadd_rn(r2, __fmul_rn(vz[i + 2], vz[i + 2]));
        r3 = __fadd_rn(r3, __fmul_rn(vz[i + 3], vz[i + 3]));
        r4 = __fadd_rn(r4, __fmul_rn(vz[i + 4], vz[i + 4]));
        r5 = __fadd_rn(r5, __fmul_rn(vz[i + 5], vz[i + 5]));
        r6 = __fadd_rn(r6, __fmul_rn(vz[i + 6], vz[i + 6]));
        r7 = __fadd_rn(r7, __fmul_rn(vz[i + 7], vz[i + 7]));
    }
    float a = __fadd_rn(r0, r1);
    float b = __fadd_rn(r2, r3);
    float c = __fadd_rn(r4, r5);
    float e = __fadd_rn(r6, r7);
    return __fadd_rn(__fadd_rn(a, b), __fadd_rn(c, e));
}

__device__ __forceinline__ void loadpt(const float* __restrict__ p, f32x64& v) {
    const float4* p4 = reinterpret_cast<const float4*>(p);
#pragma unroll
    for (int i = 0; i < DD / 4; ++i) {
        float4 t = p4[i];
        v[4 * i + 0] = t.x;
        v[4 * i + 1] = t.y;
        v[4 * i + 2] = t.z;
        v[4 * i + 3] = t.w;
    }
}

// ------------- kernel 1: argmin, 2 pts/thread, in-block K parity-split -------
// Block: 256 threads, 256 points. Threads 0..127 (waves 0,1) scan EVEN code
// indices for points {2q, 2q+1}; threads 128..255 (waves 2,3) scan ODD codes
// for the same points. Parity is wave-uniform -> LDS broadcasts. Each
// ds_read_b128 feeds 8 FMAs (2 pts x 4 elems). Grid = N/256 = 512 blocks ->
// 2 blocks/CU -> 2 waves/SIMD.
// Per-(point,code) arithmetic bit-identical to verified rounds:
//   dot  = sequential FMA d=0..63
//   dist = fl( fma(-2,dot,znorm) + cnorm )
//   per-parity argmin: strict < ascending k (first-min in class)
//   merge: dO<dE -> odd; dO==dE -> min index  == np.argmin first-min rule
__global__ __launch_bounds__(256, 2) void argmin_kernel(const float* __restrict__ z,
                                                        const float* __restrict__ cb,
                                                        const float* __restrict__ cnorm,
                                                        float* __restrict__ outIdxF,
                                                        int N, int K) {
    __shared__ float lds_cb[TK * DD];   // 64 KB
    __shared__ float lds_cn[TK];        // 1 KB
    __shared__ float sdE[256], sdO[256];
    __shared__ int   siE[256], siO[256];

    const int base = blockIdx.x * 256;          // 256 points per block
    const int q = threadIdx.x & 127;            // point pair id
    const int h = threadIdx.x >> 7;             // 0: even codes, 1: odd codes
    const int n0 = base + 2 * q;
    const int n1 = base + 2 * q + 1;

    f32x64 vz0, vz1;
    loadpt(z + (size_t)n0 * DD, vz0);
    loadpt(z + (size_t)n1 * DD, vz1);

    const float zn0 = znorm64(vz0);
    const float zn1 = znorm64(vz1);

    float best0 = 3.402823466e+38f, best1 = 3.402823466e+38f;
    int bidx0 = 0, bidx1 = 0;

    const int nTiles = K / TK;
    for (int t = 0; t < nTiles; ++t) {
        __syncthreads();   // previous tile fully consumed
        {   // cooperative stage: 16384 floats = 4096 float4, coalesced
            const float4* src = reinterpret_cast<const float4*>(cb + (size_t)t * TK * DD);
            float4* dst = reinterpret_cast<float4*>(lds_cb);
#pragma unroll
            for (int i = 0; i < (TK * DD / 4) / 256; ++i)
                dst[threadIdx.x + i * 256] = src[threadIdx.x + i * 256];
            lds_cn[threadIdx.x] = cnorm[t * TK + threadIdx.x];
        }
        __syncthreads();

        // 128 parity-class codes in this tile, 2 per iteration
#pragma unroll 2
        for (int kk = 0; kk < TK / 2; kk += 2) {
            const int cA_k = 2 * kk + h;         // wave-uniform
            const int cB_k = cA_k + 2;
            const float4* cA = reinterpret_cast<const float4*>(lds_cb + cA_k * DD);
            const float4* cB = reinterpret_cast<const float4*>(lds_cb + cB_k * DD);
            float a00 = 0.0f, a01 = 0.0f, a10 = 0.0f, a11 = 0.0f;
#pragma unroll
            for (int i = 0; i < DD / 4; ++i) {
                float4 xA = cA[i];
                float4 xB = cB[i];
                a00 = __builtin_fmaf(vz0[4 * i + 0], xA.x, a00);
                a00 = __builtin_fmaf(vz0[4 * i + 1], xA.y, a00);
                a00 = __builtin_fmaf(vz0[4 * i + 2], xA.z, a00);
                a00 = __builtin_fmaf(vz0[4 * i + 3], xA.w, a00);
                a10 = __builtin_fmaf(vz1[4 * i + 0], xA.x, a10);
                a10 = __builtin_fmaf(vz1[4 * i + 1], xA.y, a10);
                a10 = __builtin_fmaf(vz1[4 * i + 2], xA.z, a10);
                a10 = __builtin_fmaf(vz1[4 * i + 3], xA.w, a10);
                a01 = __builtin_fmaf(vz0[4 * i + 0], xB.x, a01);
                a01 = __builtin_fmaf(vz0[4 * i + 1], xB.y, a01);
                a01 = __builtin_fmaf(vz0[4 * i + 2], xB.z, a01);
                a01 = __builtin_fmaf(vz0[4 * i + 3], xB.w, a01);
                a11 = __builtin_fmaf(vz1[4 * i + 0], xB.x, a11);
                a11 = __builtin_fmaf(vz1[4 * i + 1], xB.y, a11);
                a11 = __builtin_fmaf(vz1[4 * i + 2], xB.z, a11);
                a11 = __builtin_fmaf(vz1[4 * i + 3], xB.w, a11);
            }
            float cnA = lds_cn[cA_k];
            float cnB = lds_cn[cB_k];
            float t00 = __fadd_rn(__builtin_fmaf(-2.0f, a00, zn0), cnA);
            float t01 = __fadd_rn(__builtin_fmaf(-2.0f, a01, zn0), cnB);
            float t10 = __fadd_rn(__builtin_fmaf(-2.0f, a10, zn1), cnA);
            float t11 = __fadd_rn(__builtin_fmaf(-2.0f, a11, zn1), cnB);
            int kA = t * TK + cA_k;
            int kB = kA + 2;
            if (t00 < best0) { best0 = t00; bidx0 = kA; }
            if (t01 < best0) { best0 = t01; bidx0 = kB; }
            if (t10 < best1) { best1 = t10; bidx1 = kA; }
            if (t11 < best1) { best1 = t11; bidx1 = kB; }
        }
    }

    // ---- in-block merge of even/odd candidates ----
    if (h == 0) {
        sdE[2 * q] = best0; siE[2 * q] = bidx0;
        sdE[2 * q + 1] = best1; siE[2 * q + 1] = bidx1;
    } else {
        sdO[2 * q] = best0; siO[2 * q] = bidx0;
        sdO[2 * q + 1] = best1; siO[2 * q + 1] = bidx1;
    }
    __syncthreads();
    {
        int p = threadIdx.x;                    // one point per thread
        float dE = sdE[p], dO = sdO[p];
        int iE = siE[p], iO = siO[p];
        // np.argmin first-min rule: smaller dist wins; exact tie -> smaller idx
        bool pickO = (dO < dE) || (dO == dE && iO < iE);
        outIdxF[base + p] = (float)(pickO ? iO : iE);
    }
}

// ------------- kernel 2: gather z_q, write z_q_st, loss partials -------------
__global__ __launch_bounds__(256) void gather_kernel(const float* __restrict__ z,
                                                     const float* __restrict__ cb,
                                                     const float* __restrict__ idxF,
                                                     float* __restrict__ out0,
                                                     float* __restrict__ partials,
                                                     int N) {
    int gtid = blockIdx.x * 256 + threadIdx.x;
    int wave = gtid >> 6;
    int lane = threadIdx.x & 63;
    int nwaves = (gridDim.x * 256) >> 6;

    float acc = 0.0f;
    for (int n = wave; n < N; n += nwaves) {
        int idx = (int)idxF[n];
        float q = cb[(size_t)idx * DD + lane];
        float zv = z[(size_t)n * DD + lane];
        float t = q - zv;                       // stop_gradient(z_q - z), one round
        out0[(size_t)n * DD + lane] = zv + t;   // z + sg(z_q - z), second round
        acc += t * t;                           // loss accumulation (loose tolerance)
    }
#pragma unroll
    for (int off = 32; off; off >>= 1) acc += __shfl_xor(acc, off);

    __shared__ float ws[4];
    if (lane == 0) ws[threadIdx.x >> 6] = acc;
    __syncthreads();
    if (threadIdx.x == 0) {
        float s = (ws[0] + ws[1]) + (ws[2] + ws[3]);
        partials[blockIdx.x] = s;
    }
}

// ---------------- kernel 3: finalize loss ------------------------------------
__global__ __launch_bounds__(256) void finalize_kernel(const float* __restrict__ partials,
                                                       int nPart, float* __restrict__ lossOut,
                                                       float totalElems) {
    __shared__ float sh[256];
    float s = 0.0f;
    for (int i = threadIdx.x; i < nPart; i += 256) s += partials[i];
    sh[threadIdx.x] = s;
    __syncthreads();
    for (int stride = 128; stride; stride >>= 1) {
        if (threadIdx.x < stride) sh[threadIdx.x] += sh[threadIdx.x + stride];
        __syncthreads();
    }
    if (threadIdx.x == 0) {
        float m = sh[0] / totalElems;            // 2^23 divisor -> exact
        float p = 0.25f * m;                     // exact
        lossOut[0] = __fadd_rn(p, m);            // np op order
    }
}

extern "C" void kernel_launch(void* const* d_in, const int* in_sizes, int n_in,
                              void* d_out, int out_size, void* d_ws, size_t ws_size,
                              hipStream_t stream) {
    const float* z = (const float*)d_in[0];
    const float* cb = (const float*)d_in[1];
    const int N = in_sizes[0] / DD;   // 131072
    const int K = in_sizes[1] / DD;   // 1024

    float* out0 = (float*)d_out;                       // z_q_st: N*DD floats
    float* lossOut = out0 + (size_t)N * DD;            // 1 float
    float* outIdxF = lossOut + 1;                      // N floats (indices as f32)

    float* cnorm = (float*)d_ws;                       // K floats
    float* partials = cnorm + K;                       // 2048 floats

    cnorm_kernel<<<(K + 255) / 256, 256, 0, stream>>>(cb, cnorm, K);
    argmin_kernel<<<(N + 255) / 256, 256, 0, stream>>>(z, cb, cnorm, outIdxF, N, K);

    const int nBlocks2 = 2048;
    gather_kernel<<<nBlocks2, 256, 0, stream>>>(z, cb, outIdxF, out0, partials, N);
    finalize_kernel<<<1, 256, 0, stream>>>(partials, nBlocks2, lossOut,
                                           (float)((size_t)N * DD));
}